// Round 2
// 1118.472 us; speedup vs baseline: 1.1682x; 1.1682x over previous
//
#include <hip/hip_runtime.h>

typedef __bf16 bf16_t;
typedef __bf16 bf16x8 __attribute__((ext_vector_type(8)));
typedef __bf16 bf16x4 __attribute__((ext_vector_type(4)));
typedef float  f32x4  __attribute__((ext_vector_type(4)));

#define MODE_GELU   0
#define MODE_GATED  1
#define MODE_RES_BF 2
#define MODE_RES_F  3
#define MODE_FFN2   4

__device__ __forceinline__ void async16(const void* g, void* l) {
  __builtin_amdgcn_global_load_lds(
      (const __attribute__((address_space(1))) void*)g,
      (__attribute__((address_space(3))) void*)l, 16, 0, 0);
}

// fast transcendental helpers: v_exp_f32 / v_rcp_f32 based, bf16-exact
__device__ __forceinline__ float fast_exp(float x) {
  return __builtin_amdgcn_exp2f(x * 1.44269504088896f);
}
__device__ __forceinline__ float fast_sigmoid(float x) {
  return __builtin_amdgcn_rcpf(1.0f + fast_exp(-x));
}
// gelu via Abramowitz-Stegun 7.1.26 erf approx, |eps| <= 1.5e-7
__device__ __forceinline__ float fast_gelu(float x) {
  float u = fabsf(x) * 0.70710678118f;
  float t = __builtin_amdgcn_rcpf(fmaf(0.3275911f, u, 1.0f));
  float p = t * fmaf(t, fmaf(t, fmaf(t, fmaf(t, 1.061405429f, -1.453152027f),
                                     1.421413741f), -0.284496736f), 0.254829592f);
  float e = __builtin_amdgcn_exp2f(-u * u * 1.44269504088896f);
  float erfu = fmaf(-p, e, 1.0f);
  float s = (x >= 0.f) ? erfu : -erfu;
  return 0.5f * x * (1.0f + s);
}

// ---------------------------------------------------------------------------
// GEMM: C = epilogue(A[M,K] @ B^T[N,K]) ; 128x128 tile, BK=64, 16x16x32 bf16
// ---------------------------------------------------------------------------
template<int MODE>
__launch_bounds__(256, 2)
__global__ void gemm_mfma(const bf16_t* __restrict__ A,
                          const bf16_t* __restrict__ B1,
                          const bf16_t* __restrict__ B2,
                          const float*  __restrict__ bias,
                          const float*  __restrict__ Xres,
                          const float*  __restrict__ mask,
                          void* __restrict__ Cptr,
                          int M, int N, int K, int ldC, int coff)
{
  constexpr bool DUAL = (MODE == MODE_GATED);
  __shared__ bf16_t sA[128 * 64];
  __shared__ bf16_t sB[128 * 64];
  __shared__ bf16_t sB2[DUAL ? 128 * 64 : 8];

  const int tid  = threadIdx.x;
  const int wave = tid >> 6;
  const int lane = tid & 63;
  const int wm = wave & 1;
  const int wn = wave >> 1;
  const long m0 = (long)blockIdx.y * 128;
  const long n0 = (long)blockIdx.x * 128;

  f32x4 zero4 = {0.f, 0.f, 0.f, 0.f};
  f32x4 acc[4][4];
  f32x4 acc2[DUAL ? 4 : 1][DUAL ? 4 : 1];
#pragma unroll
  for (int i = 0; i < 4; i++)
#pragma unroll
    for (int j = 0; j < 4; j++) acc[i][j] = zero4;
  if constexpr (DUAL) {
#pragma unroll
    for (int i = 0; i < 4; i++)
#pragma unroll
      for (int j = 0; j < 4; j++) acc2[i][j] = zero4;
  }

  const int q    = lane >> 4;   // 0..3
  const int c16  = lane & 15;
  const int sr   = lane >> 3;   // 0..7
  const int sg   = lane & 7;
  const int stRow = wave * 8 + sr;   // 0..31

  for (long k0 = 0; k0 < K; k0 += 64) {
#pragma unroll
    for (int i = 0; i < 4; i++) {
      int  r     = i * 32 + stRow;
      int  g     = sg ^ (r & 7);
      long goff  = (long)r * K + k0 + g * 8;
      int  lbase = i * 2048 + wave * 512;   // elements
      async16(A  + m0 * K + goff, &sA[lbase]);
      async16(B1 + n0 * K + goff, &sB[lbase]);
      if constexpr (DUAL) async16(B2 + n0 * K + goff, &sB2[lbase]);
    }
    __syncthreads();
#pragma unroll
    for (int kk = 0; kk < 2; kk++) {
      bf16x8 af[4], bfr[4], b2fr[DUAL ? 4 : 1];
#pragma unroll
      for (int i = 0; i < 4; i++) {
        int r = wm * 64 + i * 16 + c16;
        int g = (kk * 4 + q) ^ (r & 7);
        af[i] = *(const bf16x8*)&sA[r * 64 + g * 8];
      }
#pragma unroll
      for (int j = 0; j < 4; j++) {
        int r = wn * 64 + j * 16 + c16;
        int g = (kk * 4 + q) ^ (r & 7);
        bfr[j] = *(const bf16x8*)&sB[r * 64 + g * 8];
        if constexpr (DUAL) b2fr[j] = *(const bf16x8*)&sB2[r * 64 + g * 8];
      }
#pragma unroll
      for (int i = 0; i < 4; i++)
#pragma unroll
        for (int j = 0; j < 4; j++) {
          acc[i][j] = __builtin_amdgcn_mfma_f32_16x16x32_bf16(af[i], bfr[j], acc[i][j], 0, 0, 0);
          if constexpr (DUAL)
            acc2[i][j] = __builtin_amdgcn_mfma_f32_16x16x32_bf16(af[i], b2fr[j], acc2[i][j], 0, 0, 0);
        }
    }
    __syncthreads();
  }

  // epilogue: C/D layout col=lane&15, row=(lane>>4)*4+reg  [m89-verified]
#pragma unroll
  for (int i = 0; i < 4; i++) {
#pragma unroll
    for (int j = 0; j < 4; j++) {
#pragma unroll
      for (int r = 0; r < 4; r++) {
        long m = m0 + wm * 64 + i * 16 + q * 4 + r;
        long n = n0 + wn * 64 + j * 16 + c16;
        float v = acc[i][j][r];
        if constexpr (MODE == MODE_GELU) {
          float x  = v + bias[n];
          ((bf16_t*)Cptr)[m * (long)ldC + n] = (bf16_t)fast_gelu(x);
        } else if constexpr (MODE == MODE_GATED) {
          float z  = v + bias[n];
          float gt = acc2[i][j][r] + bias[N + n];
          float sz = z * fast_sigmoid(z);
          float sg_ = fast_sigmoid(gt);
          ((bf16_t*)Cptr)[m * (long)ldC + n] = (bf16_t)(sz * sg_);
        } else if constexpr (MODE == MODE_RES_BF) {
          float x = Xres[m * (long)N + n] + v + bias[n];
          ((bf16_t*)Cptr)[m * (long)ldC + coff + n] = (bf16_t)x;
        } else if constexpr (MODE == MODE_RES_F) {
          float x = Xres[m * (long)N + n] + v + bias[n];
          ((float*)Cptr)[m * (long)ldC + n] = x;
        } else {  // MODE_FFN2
          float x = (Xres[m * (long)N + n] + v + bias[n]) * mask[m];
          ((float*)Cptr)[m * (long)ldC + n] = x;
        }
      }
    }
  }
}

// ---------------------------------------------------------------------------
// transpose+cast all weights f32[K,N] -> bf16[N,K], one launch
// ---------------------------------------------------------------------------
struct TransDesc { const float* src; bf16_t* dst; int K, N, tileBase; };
struct TransArgs { TransDesc d[16]; int nd; };

__global__ void transpose_all(TransArgs args) {
  __shared__ float tile[32][33];
  int bid = blockIdx.x;
  int di = 0;
  while (di + 1 < args.nd && bid >= args.d[di + 1].tileBase) ++di;
  TransDesc d = args.d[di];
  int t = bid - d.tileBase;
  int tilesX = d.N >> 5;
  int ty = t / tilesX, tx = t % tilesX;
  int lx = threadIdx.x & 31, ly = threadIdx.x >> 5;  // 32x8
  int gx = tx * 32 + lx;
#pragma unroll
  for (int i = 0; i < 32; i += 8) {
    int gy = ty * 32 + ly + i;
    tile[ly + i][lx] = d.src[(long)gy * d.N + gx];
  }
  __syncthreads();
  int ox = ty * 32 + lx;  // k
#pragma unroll
  for (int i = 0; i < 32; i += 8) {
    int oy = tx * 32 + ly + i;  // n
    d.dst[(long)oy * d.K + ox] = (bf16_t)tile[lx][ly + i];
  }
}

// ---------------------------------------------------------------------------
// centroids: one wave per (b,k) row of attn_maps (4096 elems)
// ---------------------------------------------------------------------------
__global__ void centroid_kernel(const float* __restrict__ attn,
                                float* __restrict__ cent,
                                float* __restrict__ outCent) {
  int wave = threadIdx.x >> 6, lane = threadIdx.x & 63;
  long row = (long)blockIdx.x * 4 + wave;
  const float4* ap = (const float4*)(attn + row * 4096);
  float s = 0.f, sx = 0.f, sy = 0.f;
#pragma unroll 4
  for (int t = 0; t < 16; t++) {
    float4 v = ap[t * 64 + lane];
    int n0 = (t * 64 + lane) * 4;
    float col = (float)(n0 & 63);
    float ry  = (float)(n0 >> 6);
    float rs = v.x + v.y + v.z + v.w;
    s  += rs;
    sx += v.x * col + v.y * (col + 1.f) + v.z * (col + 2.f) + v.w * (col + 3.f);
    sy += rs * ry;
  }
#pragma unroll
  for (int o = 32; o; o >>= 1) {
    s += __shfl_down(s, o); sx += __shfl_down(sx, o); sy += __shfl_down(sy, o);
  }
  if (lane == 0) {
    float denom = s + 1e-8f;
    float cx = (sx * (1.f / 63.f)) / denom;
    float cy = (sy * (1.f / 63.f)) / denom;
    cent[row * 2] = cx;     cent[row * 2 + 1] = cy;
    outCent[row * 2] = cx;  outCent[row * 2 + 1] = cy;
  }
}

// ---------------------------------------------------------------------------
// positional encoding rows: enc[row, 256] bf16
// ---------------------------------------------------------------------------
__global__ void enc_kernel(const float* __restrict__ cent, bf16_t* __restrict__ enc) {
  int tid = blockIdx.x * 256 + threadIdx.x;
  int row = tid >> 5, j = tid & 31;
  float cx = cent[row * 2], cy = cent[row * 2 + 1];
  float freq = expf(-(float)j * 0.28782313662425572f);  // 10000^(-j/32)
  float fx = cx * freq * 3.14159f;
  float fy = cy * freq * 3.14159f;
  float fc = 0.1f * freq * 3.14159f;
  bf16_t* e = enc + (long)row * 256;
  float sc = sinf(fc), cc = cosf(fc);
  e[j]        = (bf16_t)sinf(fx);  e[32 + j]  = (bf16_t)cosf(fx);
  e[64 + j]   = (bf16_t)sinf(fy);  e[96 + j]  = (bf16_t)cosf(fy);
  e[128 + j]  = (bf16_t)sc;        e[160 + j] = (bf16_t)cc;
  e[192 + j]  = (bf16_t)sc;        e[224 + j] = (bf16_t)cc;
}

// ---------------------------------------------------------------------------
// LN kernels: one wave per 512-float row
// ---------------------------------------------------------------------------
__global__ void ln_in_kernel(const float* __restrict__ X,
                             const float* __restrict__ g1, const float* __restrict__ b1,
                             const float* __restrict__ g2, const float* __restrict__ b2,
                             bf16_t* __restrict__ O1, bf16_t* __restrict__ O2) {
  int wave = threadIdx.x >> 6, lane = threadIdx.x & 63;
  long row = (long)blockIdx.x * 4 + wave;
  const float4* xp = (const float4*)(X + row * 512);
  float4 v0 = xp[lane], v1 = xp[64 + lane];
  float s  = v0.x + v0.y + v0.z + v0.w + v1.x + v1.y + v1.z + v1.w;
  float s2 = v0.x*v0.x + v0.y*v0.y + v0.z*v0.z + v0.w*v0.w
           + v1.x*v1.x + v1.y*v1.y + v1.z*v1.z + v1.w*v1.w;
#pragma unroll
  for (int o = 32; o; o >>= 1) { s += __shfl_xor(s, o); s2 += __shfl_xor(s2, o); }
  float mean = s * (1.f / 512.f);
  float var  = s2 * (1.f / 512.f) - mean * mean;
  float rstd = rsqrtf(var + 1e-5f);
  float xs[8] = {v0.x, v0.y, v0.z, v0.w, v1.x, v1.y, v1.z, v1.w};
  int   c0 = lane * 4, c1 = 256 + lane * 4;
  bf16x4 pa, pb;
#pragma unroll
  for (int t = 0; t < 4; t++) {
    float nx = (xs[t] - mean) * rstd;
    pa[t] = (bf16_t)(nx * g1[c0 + t] + b1[c0 + t]);
    pb[t] = (bf16_t)(nx * g2[c0 + t] + b2[c0 + t]);
  }
  *(bf16x4*)&O1[row * 512 + c0] = pa;
  *(bf16x4*)&O2[row * 512 + c0] = pb;
#pragma unroll
  for (int t = 0; t < 4; t++) {
    float nx = (xs[4 + t] - mean) * rstd;
    pa[t] = (bf16_t)(nx * g1[c1 + t] + b1[c1 + t]);
    pb[t] = (bf16_t)(nx * g2[c1 + t] + b2[c1 + t]);
  }
  *(bf16x4*)&O1[row * 512 + c1] = pa;
  *(bf16x4*)&O2[row * 512 + c1] = pb;
}

__global__ void ln_dual_kernel(const float* __restrict__ U,
                               const float* __restrict__ ng, const float* __restrict__ nb,
                               const float* __restrict__ fg, const float* __restrict__ fb,
                               float* __restrict__ Y, bf16_t* __restrict__ Yln) {
  int wave = threadIdx.x >> 6, lane = threadIdx.x & 63;
  long row = (long)blockIdx.x * 4 + wave;
  const float4* xp = (const float4*)(U + row * 512);
  float4 v0 = xp[lane], v1 = xp[64 + lane];
  float s  = v0.x + v0.y + v0.z + v0.w + v1.x + v1.y + v1.z + v1.w;
  float s2 = v0.x*v0.x + v0.y*v0.y + v0.z*v0.z + v0.w*v0.w
           + v1.x*v1.x + v1.y*v1.y + v1.z*v1.z + v1.w*v1.w;
#pragma unroll
  for (int o = 32; o; o >>= 1) { s += __shfl_xor(s, o); s2 += __shfl_xor(s2, o); }
  float mean = s * (1.f / 512.f);
  float var  = s2 * (1.f / 512.f) - mean * mean;
  float rstd = rsqrtf(var + 1e-5f);
  float xs[8] = {v0.x, v0.y, v0.z, v0.w, v1.x, v1.y, v1.z, v1.w};
  int   c0 = lane * 4, c1 = 256 + lane * 4;
  float y[8];
#pragma unroll
  for (int t = 0; t < 4; t++) y[t]     = (xs[t] - mean) * rstd * ng[c0 + t] + nb[c0 + t];
#pragma unroll
  for (int t = 0; t < 4; t++) y[4 + t] = (xs[4 + t] - mean) * rstd * ng[c1 + t] + nb[c1 + t];
  float4 w0 = {y[0], y[1], y[2], y[3]}, w1 = {y[4], y[5], y[6], y[7]};
  float4* yp = (float4*)(Y + row * 512);
  yp[lane] = w0; yp[64 + lane] = w1;
  float t1 = 0.f, t2 = 0.f;
#pragma unroll
  for (int t = 0; t < 8; t++) { t1 += y[t]; t2 += y[t] * y[t]; }
#pragma unroll
  for (int o = 32; o; o >>= 1) { t1 += __shfl_xor(t1, o); t2 += __shfl_xor(t2, o); }
  float mean2 = t1 * (1.f / 512.f);
  float var2  = t2 * (1.f / 512.f) - mean2 * mean2;
  float rstd2 = rsqrtf(var2 + 1e-5f);
  bf16x4 pa;
#pragma unroll
  for (int t = 0; t < 4; t++) pa[t] = (bf16_t)((y[t] - mean2) * rstd2 * fg[c0 + t] + fb[c0 + t]);
  *(bf16x4*)&Yln[row * 512 + c0] = pa;
#pragma unroll
  for (int t = 0; t < 4; t++) pa[t] = (bf16_t)((y[4 + t] - mean2) * rstd2 * fg[c1 + t] + fb[c1 + t]);
  *(bf16x4*)&Yln[row * 512 + c1] = pa;
}

// ---------------------------------------------------------------------------
extern "C" void kernel_launch(void* const* d_in, const int* in_sizes, int n_in,
                              void* d_out, int out_size, void* d_ws, size_t ws_size,
                              hipStream_t stream) {
  const int M = 16384;             // B*K tokens
  const float* slots    = (const float*)d_in[0];
  const float* keep     = (const float*)d_in[1];
  const float* attn     = (const float*)d_in[2];
  const float* pm1_w    = (const float*)d_in[5];
  const float* pm1_b    = (const float*)d_in[6];
  const float* pm2_w    = (const float*)d_in[7];
  const float* pm2_b    = (const float*)d_in[8];
  const float* fwd_ln_g = (const float*)d_in[9];
  const float* fwd_ln_b = (const float*)d_in[10];
  const float* fwd_in_w = (const float*)d_in[11];
  const float* fwd_in_b = (const float*)d_in[12];
  const float* fwd_out_w= (const float*)d_in[13];
  const float* fwd_out_b= (const float*)d_in[14];
  const float* bwd_ln_g = (const float*)d_in[15];
  const float* bwd_ln_b = (const float*)d_in[16];
  const float* bwd_in_w = (const float*)d_in[17];
  const float* bwd_in_b = (const float*)d_in[18];
  const float* bwd_out_w= (const float*)d_in[19];
  const float* bwd_out_b= (const float*)d_in[20];
  const float* merge_w  = (const float*)d_in[21];
  const float* merge_b  = (const float*)d_in[22];
  const float* norm_g   = (const float*)d_in[23];
  const float* norm_b   = (const float*)d_in[24];
  const float* ffn_ln_g = (const float*)d_in[25];
  const float* ffn_ln_b = (const float*)d_in[26];
  const float* ffn1_w   = (const float*)d_in[27];
  const float* ffn1_b   = (const float*)d_in[28];
  const float* ffn2_w   = (const float*)d_in[29];
  const float* ffn2_b   = (const float*)d_in[30];

  char* w = (char*)d_ws;
  size_t off = 0;
  auto alloc = [&](size_t bytes) { size_t r = off; off += (bytes + 255) & ~(size_t)255; return r; };

  bf16_t* pm1t = (bf16_t*)(w + alloc(512 * 256 * 2));
  bf16_t* pm2t = (bf16_t*)(w + alloc(512 * 512 * 2));
  bf16_t *fwd_int[2], *fwd_outt[2], *bwd_int[2], *bwd_outt[2], *merget[2], *ffn1t[2], *ffn2t[2];
  for (int l = 0; l < 2; l++) {
    fwd_int[l]  = (bf16_t*)(w + alloc(2048 * 512 * 2));
    fwd_outt[l] = (bf16_t*)(w + alloc(512 * 1024 * 2));
    bwd_int[l]  = (bf16_t*)(w + alloc(2048 * 512 * 2));
    bwd_outt[l] = (bf16_t*)(w + alloc(512 * 1024 * 2));
    merget[l]   = (bf16_t*)(w + alloc(512 * 1024 * 2));
    ffn1t[l]    = (bf16_t*)(w + alloc(2048 * 512 * 2));
    ffn2t[l]    = (bf16_t*)(w + alloc(512 * 2048 * 2));
  }
  float* cent = (float*)(w + alloc((size_t)M * 2 * 4));
  float* X    = (float*)(w + alloc((size_t)M * 512 * 4));
  float* Y    = (float*)(w + alloc((size_t)M * 512 * 4));
  char* A1 = w + alloc((size_t)M * 2048 * 2);
  char* A2 = w + alloc((size_t)M * 2048 * 2);

  bf16_t* Enc = (bf16_t*)A1;
  bf16_t* P1  = (bf16_t*)A2;
  bf16_t* Xf  = (bf16_t*)A1;
  bf16_t* Xb  = (bf16_t*)(A1 + (size_t)M * 512 * 2);
  bf16_t* Gf  = (bf16_t*)A2;
  bf16_t* Gb  = (bf16_t*)(A2 + (size_t)M * 1024 * 2);
  bf16_t* FB  = (bf16_t*)A1;
  float*  U   = (float*)(A1 + (size_t)M * 1024 * 2);
  bf16_t* Yln = (bf16_t*)A2;
  bf16_t* FF1 = (bf16_t*)A1;

  // 1. transpose/cast all weights (one launch)
  TransArgs ta{};
  int nt = 0, tb = 0;
  auto addT = [&](const float* s, bf16_t* dst, int K, int N) {
    ta.d[nt].src = s; ta.d[nt].dst = dst; ta.d[nt].K = K; ta.d[nt].N = N; ta.d[nt].tileBase = tb;
    tb += (K * N) >> 10; nt++;
  };
  addT(pm1_w, pm1t, 256, 512);
  addT(pm2_w, pm2t, 512, 512);
  for (int l = 0; l < 2; l++) {
    addT(fwd_in_w  + (size_t)l * 512 * 2048, fwd_int[l],  512, 2048);
    addT(fwd_out_w + (size_t)l * 1024 * 512, fwd_outt[l], 1024, 512);
    addT(bwd_in_w  + (size_t)l * 512 * 2048, bwd_int[l],  512, 2048);
    addT(bwd_out_w + (size_t)l * 1024 * 512, bwd_outt[l], 1024, 512);
    addT(merge_w   + (size_t)l * 1024 * 512, merget[l],   1024, 512);
    addT(ffn1_w    + (size_t)l * 512 * 2048, ffn1t[l],    512, 2048);
    addT(ffn2_w    + (size_t)l * 2048 * 512, ffn2t[l],    2048, 512);
  }
  ta.nd = nt;
  transpose_all<<<tb, 256, 0, stream>>>(ta);

  // 2. centroids (also writes output tail) + positional encoding
  float* outCent = (float*)d_out + (size_t)M * 512;
  centroid_kernel<<<M / 4, 256, 0, stream>>>(attn, cent, outCent);
  enc_kernel<<<(M * 32) / 256, 256, 0, stream>>>(cent, Enc);

  // 3. pos-enc MLP: P1 = gelu(Enc@pm1+b) ; X = slots + P1@pm2 + b
  gemm_mfma<MODE_GELU><<<dim3(4, 128), 256, 0, stream>>>(
      Enc, pm1t, nullptr, pm1_b, nullptr, nullptr, P1, M, 512, 256, 512, 0);
  gemm_mfma<MODE_RES_F><<<dim3(4, 128), 256, 0, stream>>>(
      P1, pm2t, nullptr, pm2_b, slots, nullptr, X, M, 512, 512, 512, 0);

  // 4. layers (permutation math cancels: ssm is per-token)
  for (int l = 0; l < 2; l++) {
    ln_in_kernel<<<M / 4, 256, 0, stream>>>(X,
        fwd_ln_g + l * 512, fwd_ln_b + l * 512,
        bwd_ln_g + l * 512, bwd_ln_b + l * 512, Xf, Xb);
    gemm_mfma<MODE_GATED><<<dim3(8, 128), 256, 0, stream>>>(
        Xf, fwd_int[l], fwd_int[l] + (size_t)1024 * 512, fwd_in_b + l * 2048,
        nullptr, nullptr, Gf, M, 1024, 512, 1024, 0);
    gemm_mfma<MODE_GATED><<<dim3(8, 128), 256, 0, stream>>>(
        Xb, bwd_int[l], bwd_int[l] + (size_t)1024 * 512, bwd_in_b + l * 2048,
        nullptr, nullptr, Gb, M, 1024, 512, 1024, 0);
    gemm_mfma<MODE_RES_BF><<<dim3(4, 128), 256, 0, stream>>>(
        Gf, fwd_outt[l], nullptr, fwd_out_b + l * 512, X, nullptr, FB, M, 512, 1024, 1024, 0);
    gemm_mfma<MODE_RES_BF><<<dim3(4, 128), 256, 0, stream>>>(
        Gb, bwd_outt[l], nullptr, bwd_out_b + l * 512, X, nullptr, FB, M, 512, 1024, 1024, 512);
    gemm_mfma<MODE_RES_F><<<dim3(4, 128), 256, 0, stream>>>(
        FB, merget[l], nullptr, merge_b + l * 512, X, nullptr, U, M, 512, 1024, 512, 0);
    ln_dual_kernel<<<M / 4, 256, 0, stream>>>(U,
        norm_g + l * 512, norm_b + l * 512,
        ffn_ln_g + l * 512, ffn_ln_b + l * 512, Y, Yln);
    gemm_mfma<MODE_GELU><<<dim3(16, 128), 256, 0, stream>>>(
        Yln, ffn1t[l], nullptr, ffn1_b + l * 2048, nullptr, nullptr, FF1, M, 2048, 512, 2048, 0);
    // last layer's ffn2 writes slots output directly to d_out (saves 64MB copy)
    float* Xdst = (l == 1) ? (float*)d_out : X;
    gemm_mfma<MODE_FFN2><<<dim3(4, 128), 256, 0, stream>>>(
        FF1, ffn2t[l], nullptr, ffn2_b + l * 512, Y, keep, Xdst, M, 512, 2048, 512, 0);
  }
}